// Round 1
// baseline (6122.405 us; speedup 1.0000x reference)
//
#include <hip/hip_runtime.h>
#include <math.h>

// WITRAN 2D-PSGMU encoder, MI355X fp32 baseline.
// B=32, ROW=96, COL=48, D=32, H=128, swap=False (col<row).
// Folded formulation: per step t (143 steps):
//   gate[N,768] = A[N,288] @ G[288,768] + g0,  A = [xt | h_row | h_col(rolled)]
// then elementwise GRU update; h double-buffered in workspace.

namespace {

constexpr int H  = 128;
constexpr int D  = 32;
constexpr int NB = 32;            // batch
constexpr int SN = 96;            // slices (= ROW, swap=False)
constexpr int OL = 48;            // original slice len (= COL)
constexpr int SL = SN + OL - 1;   // 143
constexpr int N  = SN * NB;       // 3072 rows
constexpr int GK = D + 2 * H;     // 288  (A width; also Wf row width)
constexpr int GJ = 6 * H;         // 768  (gate width)
constexpr int RPB  = 12;          // rows per block
constexpr int NBLK = N / RPB;     // 256 blocks

__device__ __forceinline__ float sigmoidf_(float x) {
  return 1.f / (1.f + expf(-x));
}

// G[k][j]: k<32 -> x coefs; 32..159 -> h_row coefs; 160..287 -> h_col coefs.
// Wf row j layout: [rowm(128) | colm(128) | xt(32)].
__global__ void precompute_G(const float* __restrict__ Wf,
                             const float* __restrict__ Wrm,
                             const float* __restrict__ Wcm,
                             const float* __restrict__ Wrxm,
                             const float* __restrict__ Wcxm,
                             float* __restrict__ G) {
  int idx = blockIdx.x * blockDim.x + threadIdx.x;
  if (idx >= GK * GJ) return;
  int k = idx / GJ;
  int j = idx - k * GJ;
  const float* wfr = Wf + (size_t)j * GK;
  float s = 0.f;
  if (k < D) {
    for (int i = 0; i < H; ++i)
      s += wfr[i] * Wrxm[i * D + k] + wfr[H + i] * Wcxm[i * D + k];
    s += wfr[2 * H + k];
  } else if (k < D + H) {
    int h = k - D;
    for (int i = 0; i < H; ++i) s += wfr[i] * Wrm[i * H + h];
  } else {
    int h = k - D - H;
    for (int i = 0; i < H; ++i) s += wfr[H + i] * Wcm[i * H + h];
  }
  G[(size_t)k * GJ + j] = s;
}

__global__ void precompute_g0(const float* __restrict__ Wf,
                              const float* __restrict__ bf,
                              const float* __restrict__ brm,
                              const float* __restrict__ bcm,
                              const float* __restrict__ brxm,
                              const float* __restrict__ bcxm,
                              float* __restrict__ g0) {
  int j = blockIdx.x * blockDim.x + threadIdx.x;
  if (j >= GJ) return;
  const float* wfr = Wf + (size_t)j * GK;
  float s = bf[j];
  for (int i = 0; i < H; ++i)
    s += wfr[i] * (brxm[i] + brm[i]) + wfr[H + i] * (bcxm[i] + bcm[i]);
  g0[j] = s;
}

__device__ __forceinline__ void fma12(float (&acc)[3], const float4 a,
                                      const float (&w)[4][3]) {
  acc[0] = fmaf(a.x, w[0][0], acc[0]);
  acc[1] = fmaf(a.x, w[0][1], acc[1]);
  acc[2] = fmaf(a.x, w[0][2], acc[2]);
  acc[0] = fmaf(a.y, w[1][0], acc[0]);
  acc[1] = fmaf(a.y, w[1][1], acc[1]);
  acc[2] = fmaf(a.y, w[1][2], acc[2]);
  acc[0] = fmaf(a.z, w[2][0], acc[0]);
  acc[1] = fmaf(a.z, w[2][1], acc[1]);
  acc[2] = fmaf(a.z, w[2][2], acc[2]);
  acc[0] = fmaf(a.w, w[3][0], acc[0]);
  acc[1] = fmaf(a.w, w[3][1], acc[1]);
  acc[2] = fmaf(a.w, w[3][2], acc[2]);
}

// One scan step: 256 blocks x 256 threads; block handles 12 consecutive rows.
__global__ __launch_bounds__(256) void witran_step(
    const float* __restrict__ input,   // [NB, SN, OL, D]
    const float* __restrict__ G,       // [GK, GJ]
    const float* __restrict__ g0,      // [GJ]
    const float* __restrict__ hprev,   // [N, 256]  (0:128 h_row, 128:256 h_col as produced)
    float* __restrict__ hnext,         // [N, 256]
    float* __restrict__ out,           // [N, SL, 256]
    float* __restrict__ hid_row,       // [NB, SN, H]
    float* __restrict__ hid_col,       // [NB, OL, H]
    int t) {
  __shared__ float A[RPB][GK];      // 13.5 KiB
  __shared__ float gate[RPB][GJ];   // 36 KiB
  const int tid = threadIdx.x;
  const int n0 = blockIdx.x * RPB;

  // Stage A = [xt | h_row | rolled h_col] for 12 rows.
  for (int idx = tid; idx < RPB * GK; idx += 256) {
    int row = idx / GK;
    int k = idx - row * GK;
    int n = n0 + row;
    int r = n >> 5;   // n / 32
    int b = n & 31;
    float v;
    if (k < D) {
      int c = t - r;
      v = (c >= 0 && c < OL)
              ? input[(((size_t)b * SN + r) * OL + c) * D + k]
              : 0.f;
    } else if (k < D + H) {
      v = hprev[(size_t)n * 256 + (k - D)];
    } else {
      int nc = n - NB;                 // circular roll by B
      if (nc < 0) nc += N;
      v = hprev[(size_t)nc * 256 + 128 + (k - D - H)];
    }
    A[row][k] = v;
  }

  const int j0 = tid;                  // thread covers gate cols j0, j0+256, j0+512
  float acc[RPB][3];
  {
    float g00 = g0[j0], g01 = g0[j0 + 256], g02 = g0[j0 + 512];
#pragma unroll
    for (int r2 = 0; r2 < RPB; ++r2) {
      acc[r2][0] = g00; acc[r2][1] = g01; acc[r2][2] = g02;
    }
  }
  __syncthreads();

  // GEMM: double-buffered weight regs (wA/wB), 4 k's per buffer.
  float wA[4][3], wB[4][3];
  {
    const float* gq = G + j0;
#pragma unroll
    for (int kk = 0; kk < 4; ++kk) {
      wA[kk][0] = gq[(size_t)kk * GJ];
      wA[kk][1] = gq[(size_t)kk * GJ + 256];
      wA[kk][2] = gq[(size_t)kk * GJ + 512];
    }
  }
  for (int k = 0; k < GK; k += 8) {
    {
      const float* gq = G + (size_t)(k + 4) * GJ + j0;
#pragma unroll
      for (int kk = 0; kk < 4; ++kk) {
        wB[kk][0] = gq[(size_t)kk * GJ];
        wB[kk][1] = gq[(size_t)kk * GJ + 256];
        wB[kk][2] = gq[(size_t)kk * GJ + 512];
      }
    }
#pragma unroll
    for (int r2 = 0; r2 < RPB; ++r2) {
      float4 a = *reinterpret_cast<const float4*>(&A[r2][k]);
      fma12(acc[r2], a, wA);
    }
    {
      int kn = (k + 8 < GK) ? (k + 8) : 0;   // harmless dummy on last iter
      const float* gq = G + (size_t)kn * GJ + j0;
#pragma unroll
      for (int kk = 0; kk < 4; ++kk) {
        wA[kk][0] = gq[(size_t)kk * GJ];
        wA[kk][1] = gq[(size_t)kk * GJ + 256];
        wA[kk][2] = gq[(size_t)kk * GJ + 512];
      }
    }
#pragma unroll
    for (int r2 = 0; r2 < RPB; ++r2) {
      float4 a = *reinterpret_cast<const float4*>(&A[r2][k + 4]);
      fma12(acc[r2], a, wB);
    }
  }

#pragma unroll
  for (int r2 = 0; r2 < RPB; ++r2) {
    gate[r2][j0]       = acc[r2][0];
    gate[r2][j0 + 256] = acc[r2][1];
    gate[r2][j0 + 512] = acc[r2][2];
  }
  __syncthreads();

  // Elementwise GRU update + output writes.
  // gate row layout: [u_r | o_r | u_c | o_c | i_r | i_c], each H wide.
  const int i = tid & 127;
  const int half = tid >> 7;
#pragma unroll
  for (int q = 0; q < 6; ++q) {
    int row = half * 6 + q;
    int n = n0 + row;
    float ur = sigmoidf_(gate[row][i]);
    float orr = sigmoidf_(gate[row][128 + i]);
    float uc = sigmoidf_(gate[row][256 + i]);
    float oc = sigmoidf_(gate[row][384 + i]);
    float ir = tanhf(gate[row][512 + i]);
    float ic = tanhf(gate[row][640 + i]);
    float hr = A[row][D + i];
    float hc = A[row][D + H + i];
    float hrn = tanhf((1.f - ur) * hr + ur * ir) * orr;
    float hcn = tanhf((1.f - uc) * hc + uc * ic) * oc;

    hnext[(size_t)n * 256 + i] = hrn;
    hnext[(size_t)n * 256 + 128 + i] = hcn;

    size_t ob = ((size_t)n * SL + t) * 256;
    out[ob + i] = hrn;
    out[ob + 128 + i] = hcn;

    int r = n >> 5;
    int b = n & 31;
    if (t - r == OL - 1)                       // last valid input step of slice r
      hid_row[((size_t)b * SN + r) * H + i] = hrn;
    if (r == SN - 1) {                         // col hiddens from last slice
      int c = t - (SN - 1);
      if (c >= 0 && c < OL)
        hid_col[((size_t)b * OL + c) * H + i] = hcn;
    }
  }
}

}  // namespace

extern "C" void kernel_launch(void* const* d_in, const int* in_sizes, int n_in,
                              void* d_out, int out_size, void* d_ws, size_t ws_size,
                              hipStream_t stream) {
  const float* input = (const float*)d_in[0];
  const float* Wf    = (const float*)d_in[1];
  const float* bf    = (const float*)d_in[2];
  const float* Wrm   = (const float*)d_in[3];
  const float* brm   = (const float*)d_in[4];
  const float* Wcm   = (const float*)d_in[5];
  const float* bcm   = (const float*)d_in[6];
  const float* Wrxm  = (const float*)d_in[7];
  const float* brxm  = (const float*)d_in[8];
  const float* Wcxm  = (const float*)d_in[9];
  const float* bcxm  = (const float*)d_in[10];

  float* out = (float*)d_out;

  // Workspace layout (floats): G | g0 | hA | hB  (~6.9 MB total)
  float* G  = (float*)d_ws;
  float* g0 = G + (size_t)GK * GJ;
  float* hA = g0 + GJ;
  float* hB = hA + (size_t)N * 256;

  float* out1 = out;                                   // [N, SL, 256]
  float* hidr = out + (size_t)N * SL * 256;            // [NB, 1, SN, H]
  float* hidc = hidr + (size_t)NB * SN * H;            // [NB, 1, OL, H]

  hipMemsetAsync(hA, 0, (size_t)N * 256 * sizeof(float), stream);
  precompute_G<<<(GK * GJ + 255) / 256, 256, 0, stream>>>(Wf, Wrm, Wcm, Wrxm,
                                                          Wcxm, G);
  precompute_g0<<<(GJ + 255) / 256, 256, 0, stream>>>(Wf, bf, brm, bcm, brxm,
                                                      bcxm, g0);

  for (int t = 0; t < SL; ++t) {
    const float* hp = (t & 1) ? hB : hA;
    float* hn = (t & 1) ? hA : hB;
    witran_step<<<NBLK, 256, 0, stream>>>(input, G, g0, hp, hn, out1, hidr,
                                          hidc, t);
  }
}

// Round 2
// 2932.267 us; speedup vs baseline: 2.0879x; 2.0879x over previous
//
#include <hip/hip_runtime.h>
#include <math.h>

// WITRAN 2D-PSGMU encoder, MI355X. Round 2: split-bf16 MFMA step kernel.
// B=32, ROW=96, COL=48, D=32, H=128, swap=False.
// Per step t: gate[N,768] = A[N,288] @ G[288,768] + g0,
//   A = [xt | h_row | h_col(rolled)], computed as
//   Ahi@Ghi + Alo@Ghi + Ahi@Glo   (split-bf16, ~fp32 precision)
// Block = one slice (32 rows, all batches). 96 blocks x 1024 threads.

namespace {

constexpr int H  = 128;
constexpr int D  = 32;
constexpr int NB = 32;            // batch
constexpr int SN = 96;            // slices (= ROW)
constexpr int OL = 48;            // original slice len (= COL)
constexpr int SL = SN + OL - 1;   // 143
constexpr int N  = SN * NB;       // 3072 rows
constexpr int GK = D + 2 * H;     // 288
constexpr int GJ = 6 * H;         // 768
constexpr int KT = GK / 32;       // 9 k-tiles
constexpr int CT = GJ / 16;       // 48 col-tiles
constexpr int TPB = 1024;         // 16 waves
constexpr int CPW = CT / 16;      // 3 col-tiles per wave
constexpr int AP = 296;           // padded A row (shorts): 288 + 8

typedef short bf16x8 __attribute__((ext_vector_type(8)));
typedef float f32x4 __attribute__((ext_vector_type(4)));

__device__ __forceinline__ unsigned short f2bf(float f) {
  union { float f; unsigned u; } v; v.f = f;
  unsigned u = v.u;
  unsigned r = (u + 0x7fffu + ((u >> 16) & 1u)) >> 16;  // RNE (no NaN here)
  return (unsigned short)r;
}
__device__ __forceinline__ float bf2f(unsigned short h) {
  union { unsigned u; float f; } v; v.u = ((unsigned)h) << 16;
  return v.f;
}
__device__ __forceinline__ float fast_sigmoid(float x) {
  return __builtin_amdgcn_rcpf(1.f + __expf(-x));
}
__device__ __forceinline__ float fast_tanh(float x) {
  return 2.f * __builtin_amdgcn_rcpf(1.f + __expf(-2.f * x)) - 1.f;
}

// Fold weights into G[288][768] and pack into MFMA B-fragment order,
// split hi/lo bf16.  Element (k,j):
//   kt=k/32, chunk=(k%32)/8, e=k%8, c=j/16, lane=(j%16)+16*chunk
//   pidx = ((kt*CT + c)*64 + lane)*8 + e
__global__ void precompute_Gpack(const float* __restrict__ Wf,
                                 const float* __restrict__ Wrm,
                                 const float* __restrict__ Wcm,
                                 const float* __restrict__ Wrxm,
                                 const float* __restrict__ Wcxm,
                                 unsigned short* __restrict__ Ghi,
                                 unsigned short* __restrict__ Glo) {
  int idx = blockIdx.x * blockDim.x + threadIdx.x;
  if (idx >= GK * GJ) return;
  int k = idx / GJ;
  int j = idx - k * GJ;
  const float* wfr = Wf + (size_t)j * GK;  // Wf row j: [rowm(128)|colm(128)|xt(32)]
  float s = 0.f;
  if (k < D) {
    for (int i = 0; i < H; ++i)
      s += wfr[i] * Wrxm[i * D + k] + wfr[H + i] * Wcxm[i * D + k];
    s += wfr[2 * H + k];
  } else if (k < D + H) {
    int h = k - D;
    for (int i = 0; i < H; ++i) s += wfr[i] * Wrm[i * H + h];
  } else {
    int h = k - D - H;
    for (int i = 0; i < H; ++i) s += wfr[H + i] * Wcm[i * H + h];
  }
  unsigned short hi = f2bf(s);
  unsigned short lo = f2bf(s - bf2f(hi));
  int kt = k >> 5, kin = k & 31;
  int chunk = kin >> 3, e = kin & 7;
  int c = j >> 4, lane = (j & 15) + (chunk << 4);
  size_t p = ((size_t)(kt * CT + c) * 64 + lane) * 8 + e;
  Ghi[p] = hi;
  Glo[p] = lo;
}

__global__ void precompute_g0(const float* __restrict__ Wf,
                              const float* __restrict__ bf,
                              const float* __restrict__ brm,
                              const float* __restrict__ bcm,
                              const float* __restrict__ brxm,
                              const float* __restrict__ bcxm,
                              float* __restrict__ g0) {
  int j = blockIdx.x * blockDim.x + threadIdx.x;
  if (j >= GJ) return;
  const float* wfr = Wf + (size_t)j * GK;
  float s = bf[j];
  for (int i = 0; i < H; ++i)
    s += wfr[i] * (brxm[i] + brm[i]) + wfr[H + i] * (bcxm[i] + bcm[i]);
  g0[j] = s;
}

// One scan step. Block g = slice g (rows n = 32g..32g+31, all batches).
__global__ __launch_bounds__(TPB) void witran_step_mfma(
    const float* __restrict__ input,          // [NB, SN, OL, D]
    const unsigned short* __restrict__ Ghi,   // packed B-frags
    const unsigned short* __restrict__ Glo,
    const float* __restrict__ g0,             // [GJ]
    const float* __restrict__ hprev,          // [N,256]: 0:128 h_row, 128:256 h_col
    float* __restrict__ hnext,
    float* __restrict__ out,                  // [N, SL, 256]
    float* __restrict__ hid_row,              // [NB, SN, H]
    float* __restrict__ hid_col,              // [NB, OL, H]
    int t) {
  __shared__ __align__(16) unsigned short AhiS[32][AP];  // 18.5 KiB
  __shared__ __align__(16) unsigned short AloS[32][AP];  // 18.5 KiB
  __shared__ float gateS[32][772];                       // 96.5 KiB (pad 772)

  const int tid = threadIdx.x;
  const int g = blockIdx.x;      // slice index
  const int c_in = t - g;        // this slice's input column at step t

  // ---- Stage A = [xt | h_row | h_col(rolled)] as split bf16 ----
  for (int idx = tid; idx < 32 * GK; idx += TPB) {
    int row = idx / GK;          // = batch b
    int k = idx - row * GK;
    float v;
    if (k < D) {
      v = ((unsigned)c_in < (unsigned)OL)
              ? input[(((size_t)row * SN + g) * OL + c_in) * D + k]
              : 0.f;
    } else if (k < D + H) {
      v = hprev[((size_t)g * 32 + row) * 256 + (k - D)];
    } else {
      int gp = (g + SN - 1) % SN;   // roll by NB: row n reads n-32
      v = hprev[((size_t)gp * 32 + row) * 256 + 128 + (k - D - H)];
    }
    unsigned short h = f2bf(v);
    AhiS[row][k] = h;
    AloS[row][k] = f2bf(v - bf2f(h));
  }
  __syncthreads();

  // ---- MFMA: gate[32][768] = A @ G + g0 ----
  const int w = tid >> 6;        // wave 0..15
  const int lane = tid & 63;
  const int lrow = lane & 15;    // fragment row/col within tile
  const int chunk = lane >> 4;   // k-subchunk 0..3

  f32x4 acc[2][CPW];
#pragma unroll
  for (int c6 = 0; c6 < CPW; ++c6) {
    float gb = g0[16 * (w + 16 * c6) + lrow];
#pragma unroll
    for (int m = 0; m < 2; ++m) acc[m][c6] = (f32x4){gb, gb, gb, gb};
  }

  const bf16x8* __restrict__ gh = (const bf16x8*)Ghi;
  const bf16x8* __restrict__ gl = (const bf16x8*)Glo;
  for (int kt = 0; kt < KT; ++kt) {
    const int ko = kt * 32 + chunk * 8;
    bf16x8 a0h = *(const bf16x8*)&AhiS[lrow][ko];
    bf16x8 a1h = *(const bf16x8*)&AhiS[16 + lrow][ko];
    bf16x8 a0l = *(const bf16x8*)&AloS[lrow][ko];
    bf16x8 a1l = *(const bf16x8*)&AloS[16 + lrow][ko];
#pragma unroll
    for (int c6 = 0; c6 < CPW; ++c6) {
      int c = w + 16 * c6;
      size_t fi = (size_t)(kt * CT + c) * 64 + lane;
      bf16x8 bh = gh[fi];
      bf16x8 bl = gl[fi];
      acc[0][c6] = __builtin_amdgcn_mfma_f32_16x16x32_bf16(a0h, bh, acc[0][c6], 0, 0, 0);
      acc[1][c6] = __builtin_amdgcn_mfma_f32_16x16x32_bf16(a1h, bh, acc[1][c6], 0, 0, 0);
      acc[0][c6] = __builtin_amdgcn_mfma_f32_16x16x32_bf16(a0l, bh, acc[0][c6], 0, 0, 0);
      acc[1][c6] = __builtin_amdgcn_mfma_f32_16x16x32_bf16(a1l, bh, acc[1][c6], 0, 0, 0);
      acc[0][c6] = __builtin_amdgcn_mfma_f32_16x16x32_bf16(a0h, bl, acc[0][c6], 0, 0, 0);
      acc[1][c6] = __builtin_amdgcn_mfma_f32_16x16x32_bf16(a1h, bl, acc[1][c6], 0, 0, 0);
    }
  }

  // D-tile layout: col = lane&15, row = 4*(lane>>4) + reg  (verified m89/m91)
#pragma unroll
  for (int c6 = 0; c6 < CPW; ++c6) {
    int j0 = 16 * (w + 16 * c6) + lrow;
#pragma unroll
    for (int m = 0; m < 2; ++m)
#pragma unroll
      for (int r = 0; r < 4; ++r)
        gateS[m * 16 + chunk * 4 + r][j0] = acc[m][c6][r];
  }
  __syncthreads();

  // ---- Elementwise GRU update + outputs ----
  // gate row layout: [u_r | o_r | u_c | o_c | i_r | i_c], each H wide.
  const int i = tid & 127;
  const int rg = tid >> 7;       // 0..7
#pragma unroll
  for (int q = 0; q < 4; ++q) {
    int row = rg * 4 + q;
    int n = g * 32 + row;
    float ur = fast_sigmoid(gateS[row][i]);
    float orr = fast_sigmoid(gateS[row][128 + i]);
    float uc = fast_sigmoid(gateS[row][256 + i]);
    float oc = fast_sigmoid(gateS[row][384 + i]);
    float ir = fast_tanh(gateS[row][512 + i]);
    float ic = fast_tanh(gateS[row][640 + i]);
    float hr = bf2f(AhiS[row][D + i]) + bf2f(AloS[row][D + i]);
    float hc = bf2f(AhiS[row][D + H + i]) + bf2f(AloS[row][D + H + i]);
    float hrn = fast_tanh((1.f - ur) * hr + ur * ir) * orr;
    float hcn = fast_tanh((1.f - uc) * hc + uc * ic) * oc;

    hnext[(size_t)n * 256 + i] = hrn;
    hnext[(size_t)n * 256 + 128 + i] = hcn;

    size_t ob = ((size_t)n * SL + t) * 256;
    out[ob + i] = hrn;
    out[ob + 128 + i] = hcn;

    if (c_in == OL - 1)                       // last valid input step of slice g
      hid_row[((size_t)row * SN + g) * H + i] = hrn;
    if (g == SN - 1) {                        // col hiddens from last slice
      int c = t - (SN - 1);
      if ((unsigned)c < (unsigned)OL)
        hid_col[((size_t)row * OL + c) * H + i] = hcn;
    }
  }
}

}  // namespace

extern "C" void kernel_launch(void* const* d_in, const int* in_sizes, int n_in,
                              void* d_out, int out_size, void* d_ws, size_t ws_size,
                              hipStream_t stream) {
  const float* input = (const float*)d_in[0];
  const float* Wf    = (const float*)d_in[1];
  const float* bf    = (const float*)d_in[2];
  const float* Wrm   = (const float*)d_in[3];
  const float* brm   = (const float*)d_in[4];
  const float* Wcm   = (const float*)d_in[5];
  const float* bcm   = (const float*)d_in[6];
  const float* Wrxm  = (const float*)d_in[7];
  const float* brxm  = (const float*)d_in[8];
  const float* Wcxm  = (const float*)d_in[9];
  const float* bcxm  = (const float*)d_in[10];

  float* out = (float*)d_out;

  // Workspace: Ghi | Glo (shorts) | g0 | hA | hB  (~7 MB)
  unsigned short* Ghi = (unsigned short*)d_ws;
  unsigned short* Glo = Ghi + (size_t)GK * GJ;
  float* g0 = (float*)(Glo + (size_t)GK * GJ);
  float* hA = g0 + GJ;
  float* hB = hA + (size_t)N * 256;

  float* out1 = out;                                   // [N, SL, 256]
  float* hidr = out + (size_t)N * SL * 256;            // [NB, 1, SN, H]
  float* hidc = hidr + (size_t)NB * SN * H;            // [NB, 1, OL, H]

  hipMemsetAsync(hA, 0, (size_t)N * 256 * sizeof(float), stream);
  precompute_Gpack<<<(GK * GJ + 255) / 256, 256, 0, stream>>>(Wf, Wrm, Wcm,
                                                              Wrxm, Wcxm, Ghi,
                                                              Glo);
  precompute_g0<<<(GJ + 255) / 256, 256, 0, stream>>>(Wf, bf, brm, bcm, brxm,
                                                      bcxm, g0);

  for (int t = 0; t < SL; ++t) {
    const float* hp = (t & 1) ? hB : hA;
    float* hn = (t & 1) ? hA : hB;
    witran_step_mfma<<<SN, TPB, 0, stream>>>(input, Ghi, Glo, g0, hp, hn, out1,
                                             hidr, hidc, t);
  }
}